// Round 2
// baseline (614.960 us; speedup 1.0000x reference)
//
#include <hip/hip_runtime.h>

#define MDIM 8192
#define NDIM 4096
#define KDIM 4096

typedef __attribute__((ext_vector_type(8))) short short8;    // 8 bf16 = 4 VGPRs
typedef __attribute__((ext_vector_type(4))) float floatx4;   // MFMA C/D

typedef const __attribute__((address_space(1))) unsigned int* gptr_t;
typedef __attribute__((address_space(3))) unsigned int* lptr_t;

// fp32 -> bf16 round-to-nearest-even (bit trick; NaN irrelevant here)
static __device__ __forceinline__ unsigned short f2bf(float f) {
    union { float f; unsigned int u; } a; a.f = f;
    unsigned int r = a.u + 0x7FFFu + ((a.u >> 16) & 1u);
    return (unsigned short)(r >> 16);
}

// ---- kernel 1: x (fp32) -> bf16. 4096 blk x 256 thr, exactly 8 float4/thread,
// fully unrolled: all 8 loads issued before any store (latency hiding via ILP).
__global__ void cvt_x_kernel(const float* __restrict__ x, unsigned short* __restrict__ xb) {
    const int S = 4096 * 256;                    // thread count
    const int idx = blockIdx.x * 256 + threadIdx.x;
    const float4* x4 = (const float4*)x;
    ushort4* o4 = (ushort4*)xb;
    float4 v[8];
    #pragma unroll
    for (int u = 0; u < 8; ++u) v[u] = x4[idx + u * S];
    #pragma unroll
    for (int u = 0; u < 8; ++u) {
        ushort4 o;
        o.x = f2bf(v[u].x); o.y = f2bf(v[u].y); o.z = f2bf(v[u].z); o.w = f2bf(v[u].w);
        o4[idx + u * S] = o;
    }
}

// ---- kernel 2: W (fp32) -> sign(W) bf16 (+1/-1/0 exact), fused sum(|W|).
// 4096 blk x 256 thr, exactly 4 float4/thread, unrolled.
__global__ void cvt_w_kernel(const float* __restrict__ w, unsigned short* __restrict__ sb,
                             float* __restrict__ sum) {
    const int S = 4096 * 256;
    const int idx = blockIdx.x * 256 + threadIdx.x;
    const float4* w4 = (const float4*)w;
    ushort4* o4 = (ushort4*)sb;
    float4 v[4];
    #pragma unroll
    for (int u = 0; u < 4; ++u) v[u] = w4[idx + u * S];
    float s = 0.f;
    #pragma unroll
    for (int u = 0; u < 4; ++u) {
        ushort4 o;
        o.x = (unsigned short)(v[u].x > 0.f ? 0x3F80 : (v[u].x < 0.f ? 0xBF80 : 0));
        o.y = (unsigned short)(v[u].y > 0.f ? 0x3F80 : (v[u].y < 0.f ? 0xBF80 : 0));
        o.z = (unsigned short)(v[u].z > 0.f ? 0x3F80 : (v[u].z < 0.f ? 0xBF80 : 0));
        o.w = (unsigned short)(v[u].w > 0.f ? 0x3F80 : (v[u].w < 0.f ? 0xBF80 : 0));
        s += fabsf(v[u].x) + fabsf(v[u].y) + fabsf(v[u].z) + fabsf(v[u].w);
        o4[idx + u * S] = o;
    }
    #pragma unroll
    for (int off = 32; off > 0; off >>= 1) s += __shfl_down(s, off, 64);
    __shared__ float red[4];
    int lane = threadIdx.x & 63, wv = threadIdx.x >> 6;
    if (lane == 0) red[wv] = s;
    __syncthreads();
    if (threadIdx.x == 0) atomicAdd(sum, red[0] + red[1] + red[2] + red[3]);
}

// ---- kernel 3: C[m,n] = scale * sum_k A[m,k]*B[n,k]  (both K-contiguous bf16) ----
// 128x128 tile, BK=32, 256 threads = 4 waves (2x2), 4x4 acc of 16x16x32 MFMA per wave.
// XOR chunk swizzle kills the 4-way LDS bank conflict of 64B rows:
//   LDS[r][p] holds tile chunk (p ^ swz(r)), swz(r) = (r&3)^((r>>2)&3).
// Staging fetches the permuted global chunk; reads apply the inverse.
__global__ __launch_bounds__(256, 2) void gemm_kernel(
    const unsigned short* __restrict__ A,   // MDIM x KDIM bf16
    const unsigned short* __restrict__ B,   // NDIM x KDIM bf16 (sign weights)
    float* __restrict__ C,                  // MDIM x NDIM fp32
    const float* __restrict__ sum)          // sum(|W|); scale = sum / (N*K)
{
    __shared__ __align__(16) unsigned short sA[128 * 32];
    __shared__ __align__(16) unsigned short sB[128 * 32];

    const int t = threadIdx.x;
    const int lane = t & 63;
    const int wv = t >> 6;           // wave id 0..3
    const int wr = wv >> 1;          // wave row (0..1) -> 64-row slab of C tile
    const int wc = wv & 1;           // wave col (0..1) -> 64-col slab
    const int m0 = blockIdx.y * 128;
    const int n0 = blockIdx.x * 128;

    floatx4 acc[4][4] = {};

    // staging: thread t owns LDS row t/4, chunk t%4 (16B). It fetches global
    // chunk (t%4) ^ swz(row) so LDS content is the swizzled tile.
    const int srow = t >> 2;
    const int sswz = (srow & 3) ^ ((srow >> 2) & 3);
    const int scol = ((t & 3) ^ sswz) << 3;           // element offset within row
    const unsigned short* gA = A + (size_t)(m0 + srow) * KDIM + scol;
    const unsigned short* gB = B + (size_t)(n0 + srow) * KDIM + scol;
    lptr_t lA0 = (lptr_t)(sA + wv * 512);          // rows 0..63  (wave slab, bytes wv*1024)
    lptr_t lA1 = (lptr_t)(sA + 2048 + wv * 512);   // rows 64..127
    lptr_t lB0 = (lptr_t)(sB + wv * 512);
    lptr_t lB1 = (lptr_t)(sB + 2048 + wv * 512);

    // fragment read: lane holds A[m=lane&15][k=(lane>>4)*8 + j].
    // row within any 16-row group is fr (groups start at multiples of 16, so
    // swz depends only on fr); chunk = (lane>>4) ^ swz(fr).
    const int fr = lane & 15;
    const int fswz = (fr & 3) ^ ((fr >> 2) & 3);
    const int fk = (((lane >> 4)) ^ fswz) << 3;
    const unsigned short* pA = &sA[(wr * 64 + fr) * 32 + fk];
    const unsigned short* pB = &sB[(wc * 64 + fr) * 32 + fk];

    for (int k = 0; k < KDIM; k += 32) {
        __builtin_amdgcn_global_load_lds((gptr_t)(gA + k), lA0, 16, 0, 0);
        __builtin_amdgcn_global_load_lds((gptr_t)(gA + k + (size_t)64 * KDIM), lA1, 16, 0, 0);
        __builtin_amdgcn_global_load_lds((gptr_t)(gB + k), lB0, 16, 0, 0);
        __builtin_amdgcn_global_load_lds((gptr_t)(gB + k + (size_t)64 * KDIM), lB1, 16, 0, 0);
        __syncthreads();   // drains vmcnt -> LDS tiles ready

        short8 af[4], bfr[4];
        #pragma unroll
        for (int i = 0; i < 4; ++i) af[i] = *(const short8*)(pA + i * 16 * 32);
        #pragma unroll
        for (int j = 0; j < 4; ++j) bfr[j] = *(const short8*)(pB + j * 16 * 32);

        #pragma unroll
        for (int i = 0; i < 4; ++i)
            #pragma unroll
            for (int j = 0; j < 4; ++j)
                acc[i][j] = __builtin_amdgcn_mfma_f32_16x16x32_bf16(af[i], bfr[j], acc[i][j], 0, 0, 0);

        __syncthreads();   // LDS reads done before next staging overwrites
    }

    const float scale = sum[0] * (1.0f / (float)(NDIM * KDIM));
    // C/D layout: col = lane&15, row = (lane>>4)*4 + reg
    const int r0 = (lane >> 4) << 2;
    const int c = n0 + wc * 64 + (lane & 15);
    #pragma unroll
    for (int i = 0; i < 4; ++i) {
        #pragma unroll
        for (int r = 0; r < 4; ++r) {
            const int row = m0 + wr * 64 + i * 16 + r0 + r;
            float* crow = C + (size_t)row * NDIM + c;
            #pragma unroll
            for (int j = 0; j < 4; ++j)
                crow[j * 16] = acc[i][j][r] * scale;
        }
    }
}

extern "C" void kernel_launch(void* const* d_in, const int* in_sizes, int n_in,
                              void* d_out, int out_size, void* d_ws, size_t ws_size,
                              hipStream_t stream) {
    const float* x = (const float*)d_in[0];   // 8192 x 4096 fp32
    const float* w = (const float*)d_in[1];   // 4096 x 4096 fp32
    float* out = (float*)d_out;               // 8192 x 4096 fp32

    // workspace layout: [x_bf16: 67,108,864 B][signW_bf16: 33,554,432 B][sum: 4 B]
    unsigned short* xb = (unsigned short*)d_ws;
    unsigned short* wb = (unsigned short*)((char*)d_ws + (size_t)MDIM * KDIM * 2);
    float* sum = (float*)((char*)d_ws + (size_t)MDIM * KDIM * 2 + (size_t)NDIM * KDIM * 2);

    hipMemsetAsync(sum, 0, sizeof(float), stream);  // ws is poisoned 0xAA each run
    cvt_x_kernel<<<4096, 256, 0, stream>>>(x, xb);
    cvt_w_kernel<<<4096, 256, 0, stream>>>(w, wb, sum);

    dim3 grid(NDIM / 128, MDIM / 128);  // (32, 64) = 2048 blocks
    gemm_kernel<<<grid, dim3(256), 0, stream>>>(xb, wb, out, sum);
}

// Round 3
// 541.097 us; speedup vs baseline: 1.1365x; 1.1365x over previous
//
#include <hip/hip_runtime.h>

#define MDIM 8192
#define NDIM 4096
#define KDIM 4096

typedef __attribute__((ext_vector_type(8))) short short8;    // 8 bf16 = 4 VGPRs
typedef __attribute__((ext_vector_type(4))) float floatx4;   // MFMA C/D

typedef const __attribute__((address_space(1))) unsigned int* gptr_t;
typedef __attribute__((address_space(3))) unsigned int* lptr_t;

// fp32 -> bf16 round-to-nearest-even (bit trick; NaN irrelevant here)
static __device__ __forceinline__ unsigned short f2bf(float f) {
    union { float f; unsigned int u; } a; a.f = f;
    unsigned int r = a.u + 0x7FFFu + ((a.u >> 16) & 1u);
    return (unsigned short)(r >> 16);
}

// ---- kernel 1: x (fp32) -> bf16, vectorized grid-stride (R1-measured best) ----
__global__ void cvt_x_kernel(const float* __restrict__ x, unsigned short* __restrict__ xb) {
    int idx = blockIdx.x * blockDim.x + threadIdx.x;
    int stride = gridDim.x * blockDim.x;
    const float4* x4 = (const float4*)x;
    ushort4* o4 = (ushort4*)xb;
    const int n4 = (MDIM * KDIM) / 4;
    for (int i = idx; i < n4; i += stride) {
        float4 v = x4[i];
        ushort4 o;
        o.x = f2bf(v.x); o.y = f2bf(v.y); o.z = f2bf(v.z); o.w = f2bf(v.w);
        o4[i] = o;
    }
}

// ---- kernel 2: W (fp32) -> sign(W) bf16 (+1/-1/0 exact), fused sum(|W|) ----
__global__ void cvt_w_kernel(const float* __restrict__ w, unsigned short* __restrict__ sb,
                             float* __restrict__ sum) {
    int idx = blockIdx.x * blockDim.x + threadIdx.x;
    int stride = gridDim.x * blockDim.x;
    const float4* w4 = (const float4*)w;
    ushort4* o4 = (ushort4*)sb;
    const int n4 = (NDIM * KDIM) / 4;
    float s = 0.f;
    for (int i = idx; i < n4; i += stride) {
        float4 v = w4[i];
        ushort4 o;
        o.x = (unsigned short)(v.x > 0.f ? 0x3F80 : (v.x < 0.f ? 0xBF80 : 0));
        o.y = (unsigned short)(v.y > 0.f ? 0x3F80 : (v.y < 0.f ? 0xBF80 : 0));
        o.z = (unsigned short)(v.z > 0.f ? 0x3F80 : (v.z < 0.f ? 0xBF80 : 0));
        o.w = (unsigned short)(v.w > 0.f ? 0x3F80 : (v.w < 0.f ? 0xBF80 : 0));
        s += fabsf(v.x) + fabsf(v.y) + fabsf(v.z) + fabsf(v.w);
        o4[i] = o;
    }
    #pragma unroll
    for (int off = 32; off > 0; off >>= 1) s += __shfl_down(s, off, 64);
    __shared__ float red[4];
    int lane = threadIdx.x & 63, wv = threadIdx.x >> 6;
    if (lane == 0) red[wv] = s;
    __syncthreads();
    if (threadIdx.x == 0) atomicAdd(sum, red[0] + red[1] + red[2] + red[3]);
}

// ---- kernel 3: C[m,n] = scale * sum_k A[m,k]*B[n,k]  (both K-contiguous bf16) ----
// 128x128 tile, BK=64 (halves barrier-drain count vs BK=32), 256 thr = 4 waves (2x2),
// per wave 4x4 acc of 16x16x32 MFMA, 2 k-halves per LDS tile.
// LDS rows are 128B (8 x 16B chunks). XOR-8 swizzle: LDS[r][p] holds global chunk
// p ^ (r&7); staging permutes WITHIN the same 128B row segment (coalescing intact),
// fragment reads land 16 lanes on 8 distinct 4-bank groups (2-way = free).
__global__ __launch_bounds__(256, 2) void gemm_kernel(
    const unsigned short* __restrict__ A,   // MDIM x KDIM bf16
    const unsigned short* __restrict__ B,   // NDIM x KDIM bf16 (sign weights)
    float* __restrict__ C,                  // MDIM x NDIM fp32
    const float* __restrict__ sum)          // sum(|W|); scale = sum / (N*K)
{
    __shared__ __align__(16) unsigned short sA[128 * 64];   // 16 KB
    __shared__ __align__(16) unsigned short sB[128 * 64];   // 16 KB

    const int t = threadIdx.x;
    const int lane = t & 63;
    const int wv = t >> 6;           // wave id 0..3
    const int wr = wv >> 1;          // wave row (0..1) -> 64-row slab of C tile
    const int wc = wv & 1;           // wave col (0..1) -> 64-col slab
    const int m0 = blockIdx.y * 128;
    const int n0 = blockIdx.x * 128;

    floatx4 acc[4][4] = {};

    // Staging: one global_load_lds covers 64 consecutive 16B LDS chunks =
    // 8 rows x 8 chunks. Wave wv, iter i handles rows i*32 + wv*8 .. +7.
    // Lane l -> row (l>>3), physical chunk (l&7); fetch global chunk
    // (l&7) ^ ((l>>3)&7)  (row & 7 == (l>>3)&7 since slab starts are %8==0).
    const int srow = wv * 8 + (lane >> 3);
    const int scol = (((lane & 7) ^ ((lane >> 3) & 7)) << 3);  // element offset
    const unsigned short* gA = A + (size_t)(m0 + srow) * KDIM + scol;
    const unsigned short* gB = B + (size_t)(n0 + srow) * KDIM + scol;
    lptr_t lA[4], lB[4];
    #pragma unroll
    for (int i = 0; i < 4; ++i) {
        lA[i] = (lptr_t)(sA + (i * 32 + wv * 8) * 64);
        lB[i] = (lptr_t)(sB + (i * 32 + wv * 8) * 64);
    }

    // Fragment read: lane holds A[m=fr][k = kb*32 + kc*8 + j], kc = lane>>4.
    // Logical chunk = kb*4 + kc; physical = chunk ^ (fr&7) (row%16 offsets are %8==0...
    // rows wr*64 + i*16 + fr: wr*64, i*16 are %8==0, so row&7 == fr&7).
    const int fr = lane & 15;
    const int kc = lane >> 4;

    for (int k = 0; k < KDIM; k += 64) {
        #pragma unroll
        for (int i = 0; i < 4; ++i) {
            __builtin_amdgcn_global_load_lds((gptr_t)(gA + k + (size_t)(i * 32) * KDIM), lA[i], 16, 0, 0);
            __builtin_amdgcn_global_load_lds((gptr_t)(gB + k + (size_t)(i * 32) * KDIM), lB[i], 16, 0, 0);
        }
        __syncthreads();   // drains vmcnt -> LDS tiles ready

        #pragma unroll
        for (int kb = 0; kb < 2; ++kb) {
            short8 af[4], bfr[4];
            const int pa = ((kb * 4 + kc) ^ (fr & 7)) << 3;  // physical elem offset in row
            #pragma unroll
            for (int i = 0; i < 4; ++i)
                af[i] = *(const short8*)(sA + (wr * 64 + i * 16 + fr) * 64 + pa);
            #pragma unroll
            for (int j = 0; j < 4; ++j)
                bfr[j] = *(const short8*)(sB + (wc * 64 + j * 16 + fr) * 64 + pa);

            #pragma unroll
            for (int i = 0; i < 4; ++i)
                #pragma unroll
                for (int j = 0; j < 4; ++j)
                    acc[i][j] = __builtin_amdgcn_mfma_f32_16x16x32_bf16(af[i], bfr[j], acc[i][j], 0, 0, 0);
        }

        __syncthreads();   // LDS reads done before next staging overwrites
    }

    const float scale = sum[0] * (1.0f / (float)(NDIM * KDIM));
    // C/D layout: col = lane&15, row = (lane>>4)*4 + reg
    const int r0 = (lane >> 4) << 2;
    const int c = n0 + wc * 64 + (lane & 15);
    #pragma unroll
    for (int i = 0; i < 4; ++i) {
        #pragma unroll
        for (int r = 0; r < 4; ++r) {
            const int row = m0 + wr * 64 + i * 16 + r0 + r;
            float* crow = C + (size_t)row * NDIM + c;
            #pragma unroll
            for (int j = 0; j < 4; ++j)
                crow[j * 16] = acc[i][j][r] * scale;
        }
    }
}

extern "C" void kernel_launch(void* const* d_in, const int* in_sizes, int n_in,
                              void* d_out, int out_size, void* d_ws, size_t ws_size,
                              hipStream_t stream) {
    const float* x = (const float*)d_in[0];   // 8192 x 4096 fp32
    const float* w = (const float*)d_in[1];   // 4096 x 4096 fp32
    float* out = (float*)d_out;               // 8192 x 4096 fp32

    // workspace layout: [x_bf16: 67,108,864 B][signW_bf16: 33,554,432 B][sum: 4 B]
    unsigned short* xb = (unsigned short*)d_ws;
    unsigned short* wb = (unsigned short*)((char*)d_ws + (size_t)MDIM * KDIM * 2);
    float* sum = (float*)((char*)d_ws + (size_t)MDIM * KDIM * 2 + (size_t)NDIM * KDIM * 2);

    hipMemsetAsync(sum, 0, sizeof(float), stream);  // ws is poisoned 0xAA each run
    cvt_x_kernel<<<2048, 256, 0, stream>>>(x, xb);
    cvt_w_kernel<<<2048, 256, 0, stream>>>(w, wb, sum);

    dim3 grid(NDIM / 128, MDIM / 128);  // (32, 64) = 2048 blocks
    gemm_kernel<<<grid, dim3(256), 0, stream>>>(xb, wb, out, sum);
}